// Round 1
// baseline (176.529 us; speedup 1.0000x reference)
//
#include <hip/hip_runtime.h>
#include <hip/hip_bf16.h>
#include <stdint.h>

// Problem: B=8192, E=1024, P=512. x:[8192,2048] f32, w:[1024,512] f32, b:[512] f32.
// out: scalar = mean_i( -S[i,i^4096]/T + log(sum_{j!=i} exp(S[i,j]/T)) ),
// S = zn zn^T (symmetric -> upper triangle of 128x128 blocks), T=0.1.
// Pipeline: prep2 (x8 = fp8(16*relu(x)), wt8 = fp8(64*w^T), zeros) ->
// gemm1q (fp8 MX, XCD-swizzled) -> norm -> gemm2 (fp8 MX, supertile-XCD
// swizzled triangle) -> finalize.
//
// R1: 2-phase double-buffered K-loops in gemm1q/gemm2 (T3-minimum recipe):
// stage next K-tile into buf^1 BEFORE ds_read+MFMA of current buf, one
// __syncthreads() (vmcnt(0) drain) per K-step. Hides the per-step L2
// latency that the old 2-barrier structure exposed (MfmaUtil 22% -> pred ~45%).
//
// ws layout (bytes):
//   wt8 fp8  [512][1024]    @ 0
//   x8  fp8  [16384][1024]  @ 1048576
//   z   bf16 [16384][512]   @ 17825792
//   zn8 fp8  [8192][1024]   @ 68157440
//   sumexp f32[8192]        @ 84934656
//   pos    f32[8192]        @ 84967424

typedef __attribute__((ext_vector_type(8))) __bf16 bf16x8;
typedef __attribute__((ext_vector_type(4))) float f32x4;
typedef __attribute__((ext_vector_type(4))) int i32x4;
typedef __attribute__((ext_vector_type(8))) int i32x8;

__device__ __forceinline__ unsigned short f2bf(float f) {
  union { float f; unsigned int u; } v; v.f = f;
  unsigned int u = v.u;
  u += 0x7FFFu + ((u >> 16) & 1u);
  return (unsigned short)(u >> 16);
}

__device__ __forceinline__ float bf2f(unsigned short s) {
  return __uint_as_float(((unsigned int)s) << 16);
}

// ---------------- prep2: x8 = fp8(16*relu(x)); wt8 = fp8(64*w^T); zeros ------
__global__ __launch_bounds__(256) void prep2_kernel(
    const float* __restrict__ x, const float* __restrict__ w,
    unsigned char* __restrict__ x8, unsigned char* __restrict__ wt8,
    float* __restrict__ sumexp, float* __restrict__ out) {
  int tid = blockIdx.x * 256 + threadIdx.x;
  float4 v = ((const float4*)x)[tid];
  int p = __builtin_amdgcn_cvt_pk_fp8_f32(fmaxf(v.x, 0.f) * 16.f,
                                          fmaxf(v.y, 0.f) * 16.f, 0, false);
  p = __builtin_amdgcn_cvt_pk_fp8_f32(fmaxf(v.z, 0.f) * 16.f,
                                      fmaxf(v.w, 0.f) * 16.f, p, true);
  ((int*)x8)[tid] = p;
  if (tid < 512 * 1024) {
    int k = tid & 1023, n = tid >> 10;
    int q = __builtin_amdgcn_cvt_pk_fp8_f32(w[k * 512 + n] * 64.f, 0.f, 0, false);
    wt8[(n << 10) + k] = (unsigned char)(q & 0xFF);
  }
  if (tid < 8192) sumexp[tid] = 0.f;
  if (tid == 0) out[0] = 0.f;
}

// -------- gemm1q: z[16384,512](bf16) = relu(x)@w + b via fp8 MX --------------
// 128x128 tile, BK=128, XOR-swizzled LDS, 2-phase double-buffered prefetch.
// XCD-locality: grid 512 (1D); XCD x owns i-tiles [x*16,+16), n innermost ->
// per-XCD working set = 2 MB x8 band + 0.5 MB wt8 (L2-resident).
// A-frag lane L: m=L&15, k=(L>>4)*32+j. C/D: col=L&15, row=(L>>4)*4+reg.
__global__ __launch_bounds__(256, 2) void gemm1q_kernel(
    const unsigned char* __restrict__ x8, const unsigned char* __restrict__ wt8,
    const float* __restrict__ bias, unsigned short* __restrict__ z) {
  // smem: A0 @0, A1 @16384, B0 @32768, B1 @49152
  __shared__ unsigned char smem[65536] __attribute__((aligned(16)));
  int b = blockIdx.x;
  int kk = b >> 3;
  int i0 = ((b & 7) * 16 + (kk >> 2)) * 128;
  int n0 = (kk & 3) * 128;

  int tid = threadIdx.x, L = tid & 63, w = tid >> 6;
  int wm = w >> 1, wn = w & 1;
  int l4 = L & 15, q = L >> 4;
  int panel = q * 4096;

  int lp = L ^ ((L >> 3) & 7);
  int srow = w * 32 + (lp >> 1), sh = lp & 1;
  int ldst = (tid & ~63) * 16;

  f32x4 acc[4][4];
#pragma unroll
  for (int a = 0; a < 4; ++a)
#pragma unroll
    for (int bq = 0; bq < 4; ++bq) acc[a][bq] = (f32x4)0.f;

  const unsigned char* Ag = x8 + (size_t)(i0 + srow) * 1024 + sh * 16;
  const unsigned char* Bg = wt8 + (size_t)(n0 + srow) * 1024 + sh * 16;

  auto stage = [&](int buf, int k0) {
#pragma unroll
    for (int t = 0; t < 4; ++t)
      __builtin_amdgcn_global_load_lds(
          (const __attribute__((address_space(1))) void*)(Ag + k0 + t * 32),
          (__attribute__((address_space(3))) void*)(smem + buf * 16384 + t * 4096 + ldst),
          16, 0, 0);
#pragma unroll
    for (int t = 0; t < 4; ++t)
      __builtin_amdgcn_global_load_lds(
          (const __attribute__((address_space(1))) void*)(Bg + k0 + t * 32),
          (__attribute__((address_space(3))) void*)(smem + 32768 + buf * 16384 + t * 4096 + ldst),
          16, 0, 0);
  };

  auto compute = [&](int buf) {
    const unsigned char* Asb = smem + buf * 16384;
    const unsigned char* Bsb = smem + 32768 + buf * 16384;
    i32x8 afr[4];
#pragma unroll
    for (int mt = 0; mt < 4; ++mt) {
      int row = wm * 64 + mt * 16 + l4;
      int p0 = (row * 2) ^ ((row >> 2) & 7);
      i32x4 lo = *(const i32x4*)(Asb + panel + p0 * 16);
      i32x4 hi = *(const i32x4*)(Asb + panel + (p0 ^ 1) * 16);
      afr[mt] = (i32x8){lo.x, lo.y, lo.z, lo.w, hi.x, hi.y, hi.z, hi.w};
    }
#pragma unroll
    for (int nt = 0; nt < 4; ++nt) {
      int row = wn * 64 + nt * 16 + l4;
      int p0 = (row * 2) ^ ((row >> 2) & 7);
      i32x4 lo = *(const i32x4*)(Bsb + panel + p0 * 16);
      i32x4 hi = *(const i32x4*)(Bsb + panel + (p0 ^ 1) * 16);
      i32x8 bfr = (i32x8){lo.x, lo.y, lo.z, lo.w, hi.x, hi.y, hi.z, hi.w};
#pragma unroll
      for (int mt = 0; mt < 4; ++mt)
        acc[mt][nt] = __builtin_amdgcn_mfma_scale_f32_16x16x128_f8f6f4(
            afr[mt], bfr, acc[mt][nt], 0, 0,
            0, 0x7F7F7F7F, 0, 0x7F7F7F7F);
    }
  };

  stage(0, 0);
  __syncthreads();
#pragma unroll 1
  for (int k0 = 0; k0 < 1024; k0 += 256) {
    stage(1, k0 + 128);
    compute(0);
    __syncthreads();
    if (k0 < 768) stage(0, k0 + 256);
    compute(1);
    __syncthreads();
  }

  // epilogue: z = acc/1024 + bias -> bf16
  const float SC = 1.0f / 1024.0f;
#pragma unroll
  for (int nt = 0; nt < 4; ++nt) {
    int n = n0 + wn * 64 + nt * 16 + l4;
    float bn = bias[n];
#pragma unroll
    for (int mt = 0; mt < 4; ++mt) {
      int ib = i0 + wm * 64 + mt * 16 + q * 4;
#pragma unroll
      for (int r = 0; r < 4; ++r)
        z[(size_t)(ib + r) * 512 + n] = f2bf(acc[mt][nt][r] * SC + bn);
    }
  }
}

// -------- norm: zn8 = fp8_e4m3( 16 * z_row / max(||z_row||,eps) ), z bf16 ----
__global__ __launch_bounds__(256) void norm_kernel(
    const unsigned short* __restrict__ z, unsigned char* __restrict__ zn8) {
  int row = blockIdx.x, t = threadIdx.x;
  ushort4 u = ((const ushort4*)z)[row * 256 + t];
  float a0 = bf2f(u.x), a1 = bf2f(u.y), a2 = bf2f(u.z), a3 = bf2f(u.w);
  float ss = a0 * a0 + a1 * a1 + a2 * a2 + a3 * a3;
#pragma unroll
  for (int off = 1; off < 64; off <<= 1) ss += __shfl_xor(ss, off);
  __shared__ float red[4];
  if ((t & 63) == 0) red[t >> 6] = ss;
  __syncthreads();
  float tot = red[0] + red[1] + red[2] + red[3];
  float inv = 16.f / fmaxf(sqrtf(tot), 1e-8f);
  int p = __builtin_amdgcn_cvt_pk_fp8_f32(a0 * inv, a1 * inv, 0, false);
  p = __builtin_amdgcn_cvt_pk_fp8_f32(a2 * inv, a3 * inv, p, true);
  ((int*)zn8)[row * 256 + t] = p;
}

// -------- GEMM2 fp8 symmetric: 16x16x128 MX, BK=128, 2-phase dbuf ------------
// Supertile-XCD swizzle: 64x64 block-triangle partitioned into 8x8 supertiles
// of 8x8 blocks (A+B working set ~2 MB <= 4 MB per-XCD L2). Permutation
// g = (b&7)*260 + (b>>3) gives each XCD a contiguous supertile-ordered range.
// A-frag lane L: m=L&15, k=(L>>4)*32+j. C/D: col=L&15, row=(L>>4)*4+reg.
__global__ __launch_bounds__(256, 2) void gemm2_kernel(
    const unsigned char* __restrict__ zn8,
    float* __restrict__ sumexp, float* __restrict__ pos) {
  // smem: A0 @0, A1 @16384, B0 @32768, B1 @49152
  __shared__ unsigned char smem[65536] __attribute__((aligned(16)));
  // --- supertile decode (pure bijection over the 2080 triangle blocks) ---
  int g = (blockIdx.x & 7) * 260 + (blockIdx.x >> 3);
  int SI = 0, rem = g;
#pragma unroll 1
  for (SI = 0; SI < 8; ++SI) {
    int rowcnt = 36 + (7 - SI) * 64;
    if (rem < rowcnt) break;
    rem -= rowcnt;
  }
  int bi, bj;
  if (rem < 36) {                       // diagonal supertile (8x8 triangle)
    int ti = 0;
    while (rem >= 8 - ti) { rem -= 8 - ti; ++ti; }
    bi = SI * 8 + ti;
    bj = bi + rem;
  } else {                              // off-diagonal supertile
    rem -= 36;
    int SJ = SI + 1 + (rem >> 6);
    int l = rem & 63;
    bi = SI * 8 + (l >> 3);
    bj = SJ * 8 + (l & 7);
  }
  bool diag = (bi == bj);
  int i0 = bi * 128, j0 = bj * 128;

  int tid = threadIdx.x, L = tid & 63, w = tid >> 6;
  int wm = w >> 1, wn = w & 1;
  int l4 = L & 15;
  int panel = (L >> 4) * 4096;

  int lp = L ^ ((L >> 3) & 7);
  int srow = w * 32 + (lp >> 1), sh = lp & 1;
  int ldst = (tid & ~63) * 16;

  f32x4 acc[4][4];
#pragma unroll
  for (int a = 0; a < 4; ++a)
#pragma unroll
    for (int bq = 0; bq < 4; ++bq) acc[a][bq] = (f32x4)0.f;

  const unsigned char* Ag = zn8 + (i0 + srow) * 1024 + sh * 16;
  const unsigned char* Bg = zn8 + (j0 + srow) * 1024 + sh * 16;

  auto stageA = [&](int buf, int k0) {
#pragma unroll
    for (int t = 0; t < 4; ++t)
      __builtin_amdgcn_global_load_lds(
          (const __attribute__((address_space(1))) void*)(Ag + k0 + t * 32),
          (__attribute__((address_space(3))) void*)(smem + buf * 16384 + t * 4096 + ldst),
          16, 0, 0);
  };
  auto stageB = [&](int buf, int k0) {
#pragma unroll
    for (int t = 0; t < 4; ++t)
      __builtin_amdgcn_global_load_lds(
          (const __attribute__((address_space(1))) void*)(Bg + k0 + t * 32),
          (__attribute__((address_space(3))) void*)(smem + 32768 + buf * 16384 + t * 4096 + ldst),
          16, 0, 0);
  };

  auto compute = [&](int buf) {
    const unsigned char* Asb = smem + buf * 16384;
    const unsigned char* Bsb = diag ? Asb : smem + 32768 + buf * 16384;
    i32x8 afr[4];
#pragma unroll
    for (int mt = 0; mt < 4; ++mt) {
      int row = wm * 64 + mt * 16 + l4;
      int p0 = (row * 2) ^ ((row >> 2) & 7);
      i32x4 lo = *(const i32x4*)(Asb + panel + p0 * 16);
      i32x4 hi = *(const i32x4*)(Asb + panel + (p0 ^ 1) * 16);
      afr[mt] = (i32x8){lo.x, lo.y, lo.z, lo.w, hi.x, hi.y, hi.z, hi.w};
    }
#pragma unroll
    for (int nt = 0; nt < 4; ++nt) {
      int row = wn * 64 + nt * 16 + l4;
      int p0 = (row * 2) ^ ((row >> 2) & 7);
      i32x4 lo = *(const i32x4*)(Bsb + panel + p0 * 16);
      i32x4 hi = *(const i32x4*)(Bsb + panel + (p0 ^ 1) * 16);
      i32x8 bfr = (i32x8){lo.x, lo.y, lo.z, lo.w, hi.x, hi.y, hi.z, hi.w};
#pragma unroll
      for (int mt = 0; mt < 4; ++mt)
        acc[mt][nt] = __builtin_amdgcn_mfma_scale_f32_16x16x128_f8f6f4(
            afr[mt], bfr, acc[mt][nt], 0, 0,
            0, 0x7F7F7F7F, 0, 0x7F7F7F7F);
    }
  };

  stageA(0, 0);
  if (!diag) stageB(0, 0);
  __syncthreads();
#pragma unroll 1
  for (int k0 = 0; k0 < 1024; k0 += 256) {
    stageA(1, k0 + 128);
    if (!diag) stageB(1, k0 + 128);
    compute(0);
    __syncthreads();
    if (k0 < 768) {
      stageA(0, k0 + 256);
      if (!diag) stageB(0, k0 + 256);
    }
    compute(1);
    __syncthreads();
  }

  // epilogue (verified): s = acc*10/256; diag mask; pos; exp;
  // row-sums (lane bits 0-3) + col-sums (lane bits 4-5) -> atomics.
  const float SC = 10.0f / 256.0f;
  float rs[4][4];
  float cs[4] = {0.f, 0.f, 0.f, 0.f};
#pragma unroll
  for (int mt = 0; mt < 4; ++mt)
#pragma unroll
    for (int r = 0; r < 4; ++r) rs[mt][r] = 0.f;
  int ib = i0 + wm * 64 + ((L >> 4) << 2);
  int jb = j0 + wn * 64 + l4;
#pragma unroll
  for (int mt = 0; mt < 4; ++mt)
#pragma unroll
    for (int nt = 0; nt < 4; ++nt) {
      int j = jb + nt * 16;
#pragma unroll
      for (int r = 0; r < 4; ++r) {
        int i = ib + mt * 16 + r;
        float s = acc[mt][nt][r] * SC;
        if (j == (i ^ 4096)) { pos[i] = s; pos[j] = s; }
        float e = (i == j) ? 0.f : __expf(s);
        rs[mt][r] += e;
        if (!diag) cs[nt] += e;
      }
    }
#pragma unroll
  for (int mt = 0; mt < 4; ++mt)
#pragma unroll
    for (int r = 0; r < 4; ++r) {
      float v = rs[mt][r];
      v += __shfl_xor(v, 1); v += __shfl_xor(v, 2);
      v += __shfl_xor(v, 4); v += __shfl_xor(v, 8);
      rs[mt][r] = v;
    }
  int sel = l4;
  float myv = rs[0][0];
#pragma unroll
  for (int mt = 0; mt < 4; ++mt)
#pragma unroll
    for (int r = 0; r < 4; ++r)
      if (sel == mt * 4 + r) myv = rs[mt][r];
  int rowi = i0 + wm * 64 + (sel >> 2) * 16 + ((L >> 4) << 2) + (sel & 3);
  atomicAdd(&sumexp[rowi], myv);
  if (!diag) {
#pragma unroll
    for (int nt = 0; nt < 4; ++nt) {
      float v = cs[nt];
      v += __shfl_xor(v, 16); v += __shfl_xor(v, 32);
      if ((L >> 4) == 0) atomicAdd(&sumexp[jb + nt * 16], v);
    }
  }
}

// -------- finalize: out += mean-partial(log(sumexp) - pos), 16 blocks --------
__global__ __launch_bounds__(512) void finalize_kernel(
    const float* __restrict__ sumexp, const float* __restrict__ pos,
    float* __restrict__ out) {
  int t = threadIdx.x;
  int i = blockIdx.x * 512 + t;
  float s = logf(sumexp[i]) - pos[i];
#pragma unroll
  for (int off = 1; off < 64; off <<= 1) s += __shfl_xor(s, off);
  __shared__ float red[8];
  if ((t & 63) == 0) red[t >> 6] = s;
  __syncthreads();
  if (t == 0) {
    float tot = 0.f;
    for (int k2 = 0; k2 < 8; ++k2) tot += red[k2];
    atomicAdd(out, tot * (1.0f / 8192.0f));
  }
}

extern "C" void kernel_launch(void* const* d_in, const int* in_sizes, int n_in,
                              void* d_out, int out_size, void* d_ws, size_t ws_size,
                              hipStream_t stream) {
  const float* x = (const float*)d_in[0];
  const float* w = (const float*)d_in[1];
  const float* b = (const float*)d_in[2];
  float* out = (float*)d_out;
  char* ws = (char*)d_ws;
  unsigned char* wt8 = (unsigned char*)(ws);
  unsigned char* x8  = (unsigned char*)(ws + 1048576);
  unsigned short* z  = (unsigned short*)(ws + 17825792);
  unsigned char* zn8 = (unsigned char*)(ws + 68157440);
  float* sumexp      = (float*)(ws + 84934656);
  float* pos         = (float*)(ws + 84967424);

  prep2_kernel<<<16384, 256, 0, stream>>>(x, w, x8, wt8, sumexp, out);
  gemm1q_kernel<<<512, 256, 0, stream>>>(x8, wt8, b, z);
  norm_kernel<<<8192, 256, 0, stream>>>(z, zn8);
  gemm2_kernel<<<2080, 256, 0, stream>>>(zn8, sumexp, pos);
  finalize_kernel<<<16, 512, 0, stream>>>(sumexp, pos, out);
}